// Round 8
// baseline (223.561 us; speedup 1.0000x reference)
//
#include <hip/hip_runtime.h>

// GraphEmbedder: B=8, C=64, G=65536, 4 layers of y=lrelu(W@[x; x-x0]), then max over G.
// Identity: W@[x; x-x0] = Wa@x - Wb@x0, Wa = W[:,:64]+W[:,64:], Wb = W[:,64:].
// bias chain (exact fp32) in prep; main = register-resident 4-layer f16 MFMA chain.
// R8: loop inversion — layer phases outer, 4 column-tiles inner, activations in
// registers (actr[4][4] hf4); per-phase weights (8 hf8) + bias (4 float4) loaded once
// from a prep-written global f16 frag-layout array; bias is the MFMA C operand.
// No LDS in the hot path (only blockmax). launch_bounds(256,3): cap ~170 VGPR,
// above natural ~140 (R3/R5/R6: never cap below natural need).

#define G_TOT 65536

typedef _Float16 hf2 __attribute__((ext_vector_type(2)));
typedef _Float16 hf4 __attribute__((ext_vector_type(4)));
typedef _Float16 hf8 __attribute__((ext_vector_type(8)));
typedef float float4_ __attribute__((ext_vector_type(4)));

static __device__ __forceinline__ hf2 pkh(float x, float y) {
    return __builtin_bit_cast(hf2, __builtin_amdgcn_cvt_pkrtz(x, y));
}

// ws layout (floats):
//   [0, 8192)       lwsg: 16384 f16 halves — Wa in MFMA A-frag layout
//                   idx = f*512 + lane*8 + e, f=(l*4+mt)*2+pr,
//                   o=mt*16+(lane&15), c=(pr*2+(e>>2))*16+(lane>>4)*4+(e&3)
//   [8192, 10240)   nbias[b][l][o] fp32 (NEGATED bias)
//   [10240, 10752)  maxenc (uint32 ordered-float), zeroed by prep

__global__ __launch_bounds__(256) void ge_prep(
    const float* __restrict__ feat,
    const float* __restrict__ W0, const float* __restrict__ W1,
    const float* __restrict__ W2, const float* __restrict__ W3,
    float* __restrict__ ws)
{
    const int tid = threadIdx.x;
    const int blk = blockIdx.x;
    __shared__ float lw[64][129];
    __shared__ float x0[2][64];

    if (blk == 8) {
        // maxenc init + f16 frag-layout Wa
        unsigned* maxenc = (unsigned*)(ws + 10240);
        maxenc[tid] = 0u; maxenc[tid + 256] = 0u;
        unsigned short* lwsg = (unsigned short*)ws;
        for (int i = tid; i < 16384; i += 256) {
            int f = i >> 9, lane = (i >> 3) & 63, e = i & 7;
            int l = f >> 3, mt = (f >> 1) & 3, pr = f & 1;
            int o = (mt << 4) + (lane & 15);
            int c = (((pr << 1) + (e >> 2)) << 4) + ((lane >> 4) << 2) + (e & 3);
            const float* Wl = (l == 0) ? W0 : (l == 1) ? W1 : (l == 2) ? W2 : W3;
            float v = Wl[o * 128 + c] + Wl[o * 128 + 64 + c];
            lwsg[i] = __builtin_bit_cast(unsigned short, (_Float16)v);
        }
        return;
    }

    // blocks 0..7: exact fp32 bias chain for batch b = blk
    const int b = blk;
    if (tid < 64) x0[0][tid] = feat[(size_t)(b * 64 + tid) * G_TOT];
    float* nbias = ws + 8192;
    for (int l = 0; l < 4; ++l) {
        const float* Wl = (l == 0) ? W0 : (l == 1) ? W1 : (l == 2) ? W2 : W3;
        for (int i = tid; i < 64 * 128; i += 256) lw[i >> 7][i & 127] = Wl[i];
        __syncthreads();
        if (tid < 64) {
            const int o = tid;
            const float* src = x0[l & 1];
            float s1 = 0.f, s2 = 0.f;
            for (int c = 0; c < 64; ++c) {
                float xv = src[c];
                s1 += lw[o][c] * xv;
                s2 += lw[o][64 + c] * xv;
            }
            nbias[b * 256 + l * 64 + o] = -s2;          // negated, [b][l][o]
            x0[(l & 1) ^ 1][o] = fmaxf(s1, 0.1f * s1);
        }
        __syncthreads();
    }
}

__global__ __launch_bounds__(256, 3) void ge_main(
    const float* __restrict__ feat,
    const _Float16* __restrict__ lwsg,
    const float* __restrict__ nbias,
    unsigned* __restrict__ maxenc)
{
    __shared__ float blockmax[4][64];
    const int tid = threadIdx.x;
    const int b = blockIdx.x >> 8;                    // 256 blocks/batch, 256 cols each
    const int w = tid >> 6, lane = tid & 63, q = lane >> 4, n = lane & 15;
    const int g0 = ((blockIdx.x & 255) << 8) + (w << 6);   // 64 cols per wave
    const float* Xrow = feat + (size_t)b * 64 * G_TOT + (size_t)(q << 2) * G_TOT;
    const float* nb = nbias + (b << 8);
    const hf4 k01 = { (_Float16)0.1f, (_Float16)0.1f, (_Float16)0.1f, (_Float16)0.1f };

    hf4 actr[4][4];          // per-tile activations, register-resident across phases
    float rmax[4][4];
#pragma unroll
    for (int mt = 0; mt < 4; ++mt)
#pragma unroll
        for (int j = 0; j < 4; ++j) rmax[mt][j] = -__builtin_inff();

#pragma unroll
    for (int l = 0; l < 4; ++l) {
        // this layer's weights (8 hf8 = 32 VGPR) and negated bias (4 float4)
        hf8 wf[4][2];
#pragma unroll
        for (int mt = 0; mt < 4; ++mt)
#pragma unroll
            for (int pr = 0; pr < 2; ++pr)
                wf[mt][pr] = *(const hf8*)&lwsg[((((l << 2) + mt) << 1) + pr) * 512 + (lane << 3)];
        float4_ bias4[4];
#pragma unroll
        for (int mt = 0; mt < 4; ++mt)
            bias4[mt] = *(const float4_*)&nb[(l << 6) + (mt << 4) + (q << 2)];

#pragma unroll
        for (int t = 0; t < 4; ++t) {
            hf4 bf[4];
            if (l == 0) {
                const int gcol = g0 + (t << 4) + n;
                float cv[16];
#pragma unroll
                for (int kf = 0; kf < 4; ++kf)
#pragma unroll
                    for (int r = 0; r < 4; ++r)
                        cv[kf * 4 + r] = Xrow[(size_t)((kf << 4) + r) * G_TOT + gcol];
#pragma unroll
                for (int kf = 0; kf < 4; ++kf) {
                    union { hf2 h2[2]; hf4 h4; } u;
                    u.h2[0] = pkh(cv[kf * 4 + 0], cv[kf * 4 + 1]);
                    u.h2[1] = pkh(cv[kf * 4 + 2], cv[kf * 4 + 3]);
                    bf[kf] = u.h4;
                }
            } else {
#pragma unroll
                for (int kf = 0; kf < 4; ++kf) bf[kf] = actr[t][kf];
            }

            float4_ acc[4];
#pragma unroll
            for (int mt = 0; mt < 4; ++mt) {
                union { hf8 h8; hf4 h4[2]; } ua0, ua1;
                ua0.h8 = wf[mt][0];
                ua1.h8 = wf[mt][1];
                float4_ a = bias4[mt];   // bias as MFMA C operand
                a = __builtin_amdgcn_mfma_f32_16x16x16f16(ua0.h4[0], bf[0], a, 0, 0, 0);
                a = __builtin_amdgcn_mfma_f32_16x16x16f16(ua0.h4[1], bf[1], a, 0, 0, 0);
                a = __builtin_amdgcn_mfma_f32_16x16x16f16(ua1.h4[0], bf[2], a, 0, 0, 0);
                a = __builtin_amdgcn_mfma_f32_16x16x16f16(ua1.h4[1], bf[3], a, 0, 0, 0);
                acc[mt] = a;
            }

            if (l < 3) {
#pragma unroll
                for (int mt = 0; mt < 4; ++mt) {     // packed-f16 leaky-relu
                    union { hf2 h2[2]; hf4 h4; } u;
                    u.h2[0] = pkh(acc[mt][0], acc[mt][1]);
                    u.h2[1] = pkh(acc[mt][2], acc[mt][3]);
                    hf4 h = u.h4;
                    h = __builtin_elementwise_max(h, h * k01);
                    actr[t][mt] = h;     // D rows of tile mt == next-layer K-chunk mt
                }
            } else {
                // deferred lrelu: max commutes with monotone lrelu
#pragma unroll
                for (int mt = 0; mt < 4; ++mt)
#pragma unroll
                    for (int j = 0; j < 4; ++j)
                        rmax[mt][j] = fmaxf(rmax[mt][j], acc[mt][j]);
            }
        }
    }

    // reduce over 16 column-lanes, then apply the deferred lrelu once
#pragma unroll
    for (int mt = 0; mt < 4; ++mt)
#pragma unroll
        for (int j = 0; j < 4; ++j) {
            float v = rmax[mt][j];
            v = fmaxf(v, __shfl_xor(v, 1, 64));
            v = fmaxf(v, __shfl_xor(v, 2, 64));
            v = fmaxf(v, __shfl_xor(v, 4, 64));
            v = fmaxf(v, __shfl_xor(v, 8, 64));
            rmax[mt][j] = fmaxf(v, 0.1f * v);
        }
    if (n == 0) {
#pragma unroll
        for (int mt = 0; mt < 4; ++mt)
#pragma unroll
            for (int j = 0; j < 4; ++j)
                blockmax[w][(mt << 4) + (q << 2) + j] = rmax[mt][j];
    }
    __syncthreads();
    if (tid < 64) {
        float v = fmaxf(fmaxf(blockmax[0][tid], blockmax[1][tid]),
                        fmaxf(blockmax[2][tid], blockmax[3][tid]));
        unsigned s = __float_as_uint(v);
        unsigned enc = (s & 0x80000000u) ? ~s : (s | 0x80000000u);
        atomicMax(&maxenc[b * 64 + tid], enc);
    }
}

__global__ void ge_final(const unsigned* __restrict__ maxenc, float* __restrict__ out)
{
    int i = threadIdx.x;
    if (i < 512) {
        unsigned u = maxenc[i];
        unsigned s = (u & 0x80000000u) ? (u ^ 0x80000000u) : ~u;
        out[i] = __uint_as_float(s);
    }
}

extern "C" void kernel_launch(void* const* d_in, const int* in_sizes, int n_in,
                              void* d_out, int out_size, void* d_ws, size_t ws_size,
                              hipStream_t stream) {
    const float* feat = (const float*)d_in[0];
    const float* W0 = (const float*)d_in[1];
    const float* W1 = (const float*)d_in[2];
    const float* W2 = (const float*)d_in[3];
    const float* W3 = (const float*)d_in[4];
    float* ws = (float*)d_ws;
    unsigned* maxenc = (unsigned*)(ws + 10240);

    ge_prep<<<9, 256, 0, stream>>>(feat, W0, W1, W2, W3, ws);
    ge_main<<<2048, 256, 0, stream>>>(feat, (const _Float16*)ws, ws + 8192, maxenc);
    ge_final<<<1, 512, 0, stream>>>(maxenc, (float*)d_out);
}